// Round 1
// baseline (58.039 us; speedup 1.0000x reference)
//
#include <hip/hip_runtime.h>

// AdderConvReLUBlock: reference computes relu(0 - sum_{ci,ky,kx} |patch - w|).
// The accumulator is a negated sum of absolute values, hence <= 0 everywhere;
// relu() of it is identically 0.0 unless a full 3x3x32 patch exactly equals a
// weight slice (measure-zero for random normal inputs). The whole adder-conv
// is dead code behind the ReLU -> the optimal kernel is a zero-fill of d_out.
// Harness poisons d_out with 0xAA before every timed launch, so we must write
// the full 8 MB each call.

__global__ void AdderConvReLUBlock_zero_kernel(float4* __restrict__ out, int n4) {
    int i = blockIdx.x * blockDim.x + threadIdx.x;
    if (i < n4) {
        out[i] = make_float4(0.0f, 0.0f, 0.0f, 0.0f);
    }
}

extern "C" void kernel_launch(void* const* d_in, const int* in_sizes, int n_in,
                              void* d_out, int out_size, void* d_ws, size_t ws_size,
                              hipStream_t stream) {
    (void)d_in; (void)in_sizes; (void)n_in; (void)d_ws; (void)ws_size;
    // out_size = 4*32*128*128 = 2,097,152 floats, divisible by 4.
    int n4 = out_size / 4;
    int block = 256;
    int grid = (n4 + block - 1) / block;  // 2048 blocks
    AdderConvReLUBlock_zero_kernel<<<grid, block, 0, stream>>>((float4*)d_out, n4);
}